// Round 12
// baseline (129.968 us; speedup 1.0000x reference)
//
#include <hip/hip_runtime.h>
#include <stdint.h>

#define B_    32
#define D_    256
#define HW_   1024
#define N_    32768      // B_*HW_
#define K_    1024
#define BETA_ 0.25f
#define OUT0  8388608    // N_*D_

#define GRID_MAIN 512    // argmin blocks (kernel 2)
#define GRID_PREP 320    // 256 z-transpose/stat blocks + 64 E blocks (kernel 1)

typedef short bf16x8 __attribute__((ext_vector_type(8)));
typedef unsigned int u32x4 __attribute__((ext_vector_type(4)));
typedef float f32x4  __attribute__((ext_vector_type(4)));

// ---- workspace layout (bytes) ----
#define E2_OFF    0          // 512 KB  bf16 of E, A-fragment order (k-major)
#define ENORM_OFF 524288     // 4 KB    ||e_k||^2 fp32 (exact, from fp32 e)
#define SUMED_OFF 528384     // 1 KB    col sums of E
#define SUMZD_OFF 529408     // 1 KB    per-d sums of Z
#define CNT_OFF   530432     // 4 KB    histogram
#define SCAL_OFF  534528     // 32 B    doubles: [1]=sum z^2, [2]=sum diff^2
#define DONE_OFF  534560     // 4 B     last-block ticket
#define Z2_OFF    1048576    // 16 MB   bf16 of Z, B-fragment order [b][hwblk][ds][slot][8]
#define ZN2P_OFF  17825792   // 1 MB    per-(ds,n) partial ||z_n||^2 fp32 [8][32768]
#define ZERO_OFF  SUMED_OFF
#define ZERO_BYTES (534592 - SUMED_OFF)

__device__ __forceinline__ unsigned short f2bf(float f) {
  unsigned int u = __float_as_uint(f);
  u += 0x7FFFu + ((u >> 16) & 1u);          // round-to-nearest-even
  return (unsigned short)(u >> 16);
}

__device__ __forceinline__ unsigned long long pack64(float v, int k) {
  unsigned int b = __float_as_uint(v);
  b = (b & 0x80000000u) ? ~b : (b | 0x80000000u);   // order-preserving map
  return ((unsigned long long)b << 32) | (unsigned int)k;
}

__device__ __forceinline__ float unpack32(unsigned int p) {
  p = (p & 0x80000000u) ? (p ^ 0x80000000u) : ~p;
  return __uint_as_float(p);
}

__device__ __forceinline__ float blockReduceSum(float v, volatile float* sred) {
  #pragma unroll
  for (int off = 32; off > 0; off >>= 1) v += __shfl_down(v, off, 64);
  __syncthreads();
  if ((threadIdx.x & 63) == 0) sred[threadIdx.x >> 6] = v;
  __syncthreads();
  float r = 0.0f;
  if (threadIdx.x == 0) {
    const int nw = blockDim.x >> 6;
    for (int i = 0; i < nw; ++i) r += sred[i];
  }
  return r;  // valid on thread 0 only
}

// ---------------------------------------------------------------------------
// prep (unchanged from R11): blocks 0..255 stream z, LDS-transpose, emit Z2
// (bf16, exact Zs fragment order) + zn2p + z stats.  Blocks 256..319: E prep.
// ---------------------------------------------------------------------------
__global__ __launch_bounds__(512)
void vq_prep(const float* __restrict__ z, const float* __restrict__ e,
             unsigned short* __restrict__ E2, unsigned short* __restrict__ Z2,
             float* __restrict__ enorm, float* __restrict__ sum_e_d,
             float* __restrict__ sum_z_d, float* __restrict__ zn2p,
             double* __restrict__ scald) {
  __shared__ float tile[32][129];     // 16.5 KB transpose tile (+1 pad: 2-way free)
  __shared__ float ered[16][33];
  __shared__ float sumed[256];
  __shared__ float sred[8];
  const int t   = threadIdx.x;
  const int blk = blockIdx.x;

  if (blk < 256) {
    // ---- z block: b = blk>>3, ds = blk&7 (32-d slice x 1024 hw) ----
    const int b = blk >> 3, ds = blk & 7;
    const int r = t >> 4, c = t & 15;          // load identity (rows of z)
    const int l = t & 63;
    const int hwblk_l = t >> 8;                 // transpose identity: 0/1
    const int slot = t & 255;
    const int squad = (l >> 4) & 3;             // = (slot>>4)&3
    const int ni = slot >> 6;                   // const per wave
    const int n15 = l & 15;
    const int hw_loc = hwblk_l * 64 + ni * 16 + n15;
    const float* zr = z + ((size_t)(b * D_ + ds * 32 + r)) * HW_;

    float srow = 0.0f, s2 = 0.0f;
    float4 f0 = *(const float4*)(zr + c * 4);
    float4 f1 = *(const float4*)(zr + c * 4 + 64);
    #pragma unroll 1
    for (int iter = 0; iter < 8; ++iter) {
      // accumulate row stats + stage tile
      srow += (f0.x + f0.y) + (f0.z + f0.w) + (f1.x + f1.y) + (f1.z + f1.w);
      s2 += f0.x*f0.x + f0.y*f0.y + f0.z*f0.z + f0.w*f0.w
          + f1.x*f1.x + f1.y*f1.y + f1.z*f1.z + f1.w*f1.w;
      float* td = &tile[r][c * 4];
      td[0]=f0.x; td[1]=f0.y; td[2]=f0.z; td[3]=f0.w;
      td[64]=f1.x; td[65]=f1.y; td[66]=f1.z; td[67]=f1.w;
      __syncthreads();
      // prefetch next tile (latency hides under transpose phase)
      if (iter < 7) {
        f0 = *(const float4*)(zr + (iter+1) * 128 + c * 4);
        f1 = *(const float4*)(zr + (iter+1) * 128 + c * 4 + 64);
      }
      // transpose out: 8 d-consecutive values for (hw_loc) -> one bf16x8
      float v[8]; float zsq = 0.0f;
      #pragma unroll
      for (int j = 0; j < 8; ++j) {
        v[j] = tile[squad * 8 + j][hw_loc];     // banks 2-way (129%32==1)
        zsq = fmaf(v[j], v[j], zsq);
      }
      unsigned int wd[4];
      #pragma unroll
      for (int j2 = 0; j2 < 4; ++j2)
        wd[j2] = (unsigned int)f2bf(v[2*j2]) | ((unsigned int)f2bf(v[2*j2+1]) << 16);
      const size_t zi = (((size_t)(b * 16 + iter * 2 + hwblk_l)) * 8 + ds) * 256 + slot;
      *(u32x4*)(Z2 + zi * 8) = *(u32x4*)wd;     // 16B coalesced store
      // per-n ||z||^2 partial over this block's 32 d: reduce across squads
      zsq += __shfl_xor(zsq, 16, 64);
      zsq += __shfl_xor(zsq, 32, 64);
      if (squad == 0)
        zn2p[ds * N_ + b * HW_ + iter * 128 + hw_loc] = zsq;  // unique writer
      __syncthreads();
    }
    float ssum = srow;
    #pragma unroll
    for (int off = 1; off < 16; off <<= 1) ssum += __shfl_xor(ssum, off, 16);
    if (c == 0) atomicAdd(&sum_z_d[ds * 32 + r], ssum);
    const float rs2 = blockReduceSum(s2, sred);
    if (t == 0) atomicAdd(&scald[1], (double)rs2);
  } else {
    // ---- E block (kt = blk-256): R0 E-part verbatim ----
    const int kt = blk - 256;
    const int ds = t >> 6, l = t & 63;
    const int q  = l >> 4, m = l & 15;
    const int k  = kt * 16 + m;
    const int d0 = ds * 32 + q * 8;
    if (t < 256) sumed[t] = 0.0f;
    __syncthreads();

    const float* ep = e + (size_t)k * D_ + d0;
    const float4 v0 = *(const float4*)ep;
    const float4 v1 = *(const float4*)(ep + 4);
    const float vv[8] = {v0.x, v0.y, v0.z, v0.w, v1.x, v1.y, v1.z, v1.w};
    short hv[8];
    float p = 0.0f;
    #pragma unroll
    for (int j = 0; j < 8; ++j) {
      const float f = vv[j];
      p += f * f;
      hv[j] = (short)f2bf(f);
      float s = f;
      #pragma unroll
      for (int off = 1; off < 16; off <<= 1) s += __shfl_xor(s, off, 16);
      if ((l & 15) == 0) atomicAdd(&sumed[d0 + j], s);
    }
    const size_t fi = ((size_t)(kt * 8 + ds)) * 64 + l;
    *(bf16x8*)(E2 + fi * 8) = *(bf16x8*)hv;

    ered[m][ds * 4 + q] = p;
    __syncthreads();
    if (t < 16) {
      float s = 0.0f;
      #pragma unroll
      for (int i = 0; i < 32; ++i) s += ered[t][i];
      enorm[kt * 16 + t] = s;
    }
    if (t < 256) atomicAdd(&sum_e_d[t], sumed[t]);
  }
}

// ---------------------------------------------------------------------------
// R12 argmin: Phase B/C restructured 4 passes x kti=2  ->  2 passes x kti=4.
// R11 post-mortem: B/C is LDS-instruction-bound -- 512 ds_read_b32/thread
// (B-fragments re-read once per pass) = ~20us/CU vs 8.3us MFMA.  kti=4 feeds
// each B-read 4 MFMAs instead of 2: B-LDS reads halve to 256 dw/thread, fold
// runs 2x not 4x.  acc[4][4]+Av[4] fits the 128-VGPR cap of (512,4); Bv kept
// scalar-per-ni to bound liveness.  Per-thread k still strictly ascending
// (kti inner, p outer) -> first-min tiebreak preserved.
// Phases A/D, finalize: byte-identical to R11.
// ---------------------------------------------------------------------------
__global__ __launch_bounds__(512, 4)
void vq_argmin8(const float* __restrict__ e,
                const unsigned short* __restrict__ E2,
                const unsigned short* __restrict__ Z2,
                const float* __restrict__ enorm_g,
                const float* __restrict__ zn2p,
                float* __restrict__ out, unsigned int* __restrict__ counts,
                float* __restrict__ sum_e_d, float* __restrict__ sum_z_d,
                double* __restrict__ scald, unsigned int* __restrict__ done) {
  union SM {
    unsigned int Zs[8][1280];       // 40960 B: [ds][slot*5 + dword]
    float erow[32 * 257];           // 32896 B (epilogue staging, 32 n / pass)
  };
  __shared__ SM sm;
  __shared__ float en[1024];
  __shared__ unsigned long long red[8][64];
  __shared__ unsigned int kbuf[64];
  __shared__ float rs[8];
  __shared__ int sflag;

  const int t  = threadIdx.x;
  const int nt = blockIdx.x;
  const int b   = nt >> 4;
  const int hw0 = (nt & 15) << 6;
  const int w = t >> 6, l = t & 63;
  const int quad = l >> 4;
  const int slot = t & 255;
  const int jh   = t >> 8;

  en[t] = enorm_g[t];
  en[t + 512] = enorm_g[t + 512];

  // ---- Phase A: 4 x bf16x8 coalesced loads of pre-packed Z2 -> Zs ----
  {
    const bf16x8* __restrict__ Z8 = (const bf16x8*)Z2;
    const size_t z2b = (((size_t)(b * 16 + (nt & 15))) * 8) * 256;
    #pragma unroll
    for (int i = 0; i < 4; ++i) {
      const int ds = i * 2 + jh;
      const u32x4 wv = __builtin_bit_cast(u32x4, Z8[z2b + (size_t)ds * 256 + slot]);
      unsigned int* zp = &sm.Zs[ds][slot * 5];
      zp[0] = wv.x; zp[1] = wv.y; zp[2] = wv.z; zp[3] = wv.w;  // banks 2-way, free
    }
  }
  __syncthreads();

  // ---- Phase B/C: 2 passes of 128k x 64n (kti=4), fold between passes ----
  const bf16x8* __restrict__ E8 = (const bf16x8*)E2;

  float bestv[4];
  int   bestk[4];
  #pragma unroll
  for (int ni = 0; ni < 4; ++ni) { bestv[ni] = 3.0e38f; bestk[ni] = 0; }

  #pragma unroll 1
  for (int p = 0; p < 2; ++p) {
    // ktg strictly ascending per thread across p and kti => tiebreak holds
    const int ktg0 = p * 32 + w * 4;

    f32x4 acc[4][4];
    #pragma unroll
    for (int kti = 0; kti < 4; ++kti)
      #pragma unroll
      for (int ni = 0; ni < 4; ++ni) acc[kti][ni] = (f32x4)0.0f;

    #pragma unroll 2
    for (int ds = 0; ds < 8; ++ds) {
      bf16x8 Av[4];
      #pragma unroll
      for (int kti = 0; kti < 4; ++kti)
        Av[kti] = E8[(size_t)((ktg0 + kti) * 8 + ds) * 64 + l];
      #pragma unroll
      for (int ni = 0; ni < 4; ++ni) {
        const int sb = (ni * 64 + l) * 5;
        u32x4 bw;
        bw.x = sm.Zs[ds][sb + 0];     // banks (5l + j) % 32: all 32, 2-way, free
        bw.y = sm.Zs[ds][sb + 1];
        bw.z = sm.Zs[ds][sb + 2];
        bw.w = sm.Zs[ds][sb + 3];
        const bf16x8 Bv = __builtin_bit_cast(bf16x8, bw);
        #pragma unroll
        for (int kti = 0; kti < 4; ++kti)
          acc[kti][ni] = __builtin_amdgcn_mfma_f32_16x16x32_bf16(Av[kti], Bv,
                                                                acc[kti][ni], 0, 0, 0);
      }
    }
    // fold this pass (k ascending within pass as well)
    #pragma unroll
    for (int kti = 0; kti < 4; ++kti) {
      const int kb = (ktg0 + kti) * 16 + quad * 4;
      const f32x4 en4 = *(const f32x4*)&en[kb];
      #pragma unroll
      for (int ni = 0; ni < 4; ++ni) {
        const f32x4 a = acc[kti][ni];
        #pragma unroll
        for (int r = 0; r < 4; ++r) {
          const float v = fmaf(-2.0f, a[r], en4[r]);
          if (v < bestv[ni]) { bestv[ni] = v; bestk[ni] = kb + r; }
        }
      }
    }
  }

  #pragma unroll
  for (int ni = 0; ni < 4; ++ni) {
    unsigned long long p = pack64(bestv[ni], bestk[ni]);
    unsigned long long p2 = __shfl_down(p, 32, 64); if (p2 < p) p = p2;
    p2 = __shfl_down(p, 16, 64);                    if (p2 < p) p = p2;
    if (quad == 0) red[w][ni * 16 + (l & 15)] = p;
  }
  __syncthreads();   // red ready; all Zs reads done

  if (t < 64) {
    unsigned long long m = red[0][t];
    #pragma unroll
    for (int i = 1; i < 8; ++i) { const unsigned long long c = red[i][t]; if (c < m) m = c; }
    const unsigned int k = (unsigned int)(m & 0xFFFFFFFFull);
    kbuf[t] = k;
    atomicAdd(&counts[k], 1u);
    const float dminv = unpack32((unsigned int)(m >> 32));
    float zn2v = 0.0f;
    #pragma unroll
    for (int ds = 0; ds < 8; ++ds) zn2v += zn2p[ds * N_ + b * HW_ + hw0 + t];
    float dsum = zn2v + dminv;       // ||z_n - e_k||^2 (analytic)
    #pragma unroll
    for (int off = 32; off > 0; off >>= 1) dsum += __shfl_down(dsum, off, 64);
    if (t == 0) atomicAdd(&scald[2], (double)dsum);
  }
  __syncthreads();   // kbuf ready; Zs dead -> erow may overwrite

  // ---- Phase D: two 32-n passes: stage chosen e-rows, write coalesced ----
  #pragma unroll 1
  for (int p = 0; p < 2; ++p) {
    {
      const int r = t >> 4;             // 0..31 (n within pass)
      const int c = t & 15;
      const unsigned int k = kbuf[p * 32 + r];
      const float* er = e + (size_t)k * D_ + c * 4;
      #pragma unroll
      for (int i = 0; i < 4; ++i) {
        const float4 f = *(const float4*)(er + i * 64);
        float* dst = &sm.erow[r * 257 + c * 4 + i * 64];
        dst[0] = f.x; dst[1] = f.y; dst[2] = f.z; dst[3] = f.w;  // banks r+4c+j: 2-way
      }
    }
    __syncthreads();
    {
      const int s  = t >> 5;            // 0..15 -> d-slice of 16
      const int cc = t & 31;            // hw within pass
      float* ob = out + ((size_t)b * D_ + s * 16) * HW_ + hw0 + p * 32 + cc;
      #pragma unroll
      for (int i = 0; i < 16; ++i)
        ob[(size_t)i * HW_] = sm.erow[cc * 257 + s * 16 + i];
    }
    __syncthreads();
  }

  // ---- last-of-512 ticket -> finalize (NO threadfence: atomics only) ----
  if (t == 0) {
    asm volatile("s_waitcnt vmcnt(0)" ::: "memory");
    const unsigned int r = atomicAdd(done, 1u);
    sflag = (r == (GRID_MAIN - 1)) ? 1 : 0;
  }
  __syncthreads();
  if (sflag) {
    // entropy of e_mean (atomic RMW reads: coherent-point, no stale L2)
    float h = 0.0f;
    for (int i = t; i < K_; i += 512) {
      const float em = (float)atomicAdd(&counts[i], 0u) * (1.0f / (float)N_);
      h += em * logf(em + 1e-10f);
    }
    const float hs = blockReduceSum(h, rs);
    __syncthreads();
    float dv = 0.0f;
    if (t < 256) dv = atomicAdd(&sum_z_d[t], 0.0f) * sum_e_d[t];
    const float dot = blockReduceSum(dv, rs);
    __syncthreads();
    const float e2 = enorm_g[t] + enorm_g[t + 512];
    const float sume2 = blockReduceSum(e2, rs);
    if (t == 0) {
      const double sz2 = atomicAdd(&scald[1], 0.0);
      const double sd2 = atomicAdd(&scald[2], 0.0);
      const double loss = (double)(1.0f + BETA_) * sd2 / (double)((size_t)N_ * D_);
      const double md = sz2 / (double)N_ + (double)sume2 / (double)K_
                      - 2.0 * (double)dot / ((double)N_ * (double)K_);
      out[OUT0 + 0] = (float)loss;
      out[OUT0 + 1] = expf(-hs);
      out[OUT0 + 2] = (float)md;
    }
  }
}

extern "C" void kernel_launch(void* const* d_in, const int* in_sizes, int n_in,
                              void* d_out, int out_size, void* d_ws, size_t ws_size,
                              hipStream_t stream) {
  const float* z = (const float*)d_in[0];        // [32,256,32,32]
  const float* e = (const float*)d_in[1];        // [1024,256]
  float* out = (float*)d_out;

  char* ws = (char*)d_ws;
  unsigned short* E2 = (unsigned short*)(ws + E2_OFF);
  unsigned short* Z2 = (unsigned short*)(ws + Z2_OFF);
  float* enorm   = (float*)(ws + ENORM_OFF);
  float* sum_e_d = (float*)(ws + SUMED_OFF);
  float* sum_z_d = (float*)(ws + SUMZD_OFF);
  float* zn2p    = (float*)(ws + ZN2P_OFF);
  unsigned int* counts = (unsigned int*)(ws + CNT_OFF);
  double* scald  = (double*)(ws + SCAL_OFF);
  unsigned int* done = (unsigned int*)(ws + DONE_OFF);

  hipMemsetAsync(ws + ZERO_OFF, 0x00, (size_t)ZERO_BYTES, stream);

  vq_prep    <<<dim3(GRID_PREP), dim3(512), 0, stream>>>(z, e, E2, Z2, enorm,
                                                         sum_e_d, sum_z_d, zn2p, scald);
  vq_argmin8 <<<dim3(GRID_MAIN), dim3(512), 0, stream>>>(e, E2, Z2, enorm, zn2p,
                                                         out, counts, sum_e_d,
                                                         sum_z_d, scald, done);
}

// Round 16
// 128.363 us; speedup vs baseline: 1.0125x; 1.0125x over previous
//
#include <hip/hip_runtime.h>
#include <stdint.h>

#define B_    32
#define D_    256
#define HW_   1024
#define N_    32768      // B_*HW_
#define K_    1024
#define BETA_ 0.25f
#define OUT0  8388608    // N_*D_

#define GRID_MAIN 512    // argmin blocks (kernel 2)
#define GRID_PREP 320    // 256 z-transpose/stat blocks + 64 E blocks (kernel 1)

typedef short bf16x8 __attribute__((ext_vector_type(8)));
typedef unsigned int u32x4 __attribute__((ext_vector_type(4)));
typedef unsigned int u32x2 __attribute__((ext_vector_type(2)));
typedef float f32x4  __attribute__((ext_vector_type(4)));

// ---- workspace layout (bytes) ----
#define E2_OFF    0          // 512 KB  bf16 of E, A-fragment order (k-major)
#define ENORM_OFF 524288     // 4 KB    ||e_k||^2 fp32 (exact, from fp32 e)
#define SUMED_OFF 528384     // 1 KB    col sums of E
#define SUMZD_OFF 529408     // 1 KB    per-d sums of Z
#define CNT_OFF   530432     // 4 KB    histogram
#define SCAL_OFF  534528     // 32 B    doubles: [1]=sum z^2, [2]=sum diff^2
#define DONE_OFF  534560     // 4 B     last-block ticket
#define Z2_OFF    1048576    // 16 MB   bf16 of Z, B-fragment order [b][hwblk][ds][slot][8]
#define ZN2P_OFF  17825792   // 1 MB    per-(ds,n) partial ||z_n||^2 fp32 [8][32768]
#define ZERO_OFF  SUMED_OFF
#define ZERO_BYTES (534592 - SUMED_OFF)

__device__ __forceinline__ unsigned short f2bf(float f) {
  unsigned int u = __float_as_uint(f);
  u += 0x7FFFu + ((u >> 16) & 1u);          // round-to-nearest-even
  return (unsigned short)(u >> 16);
}

__device__ __forceinline__ unsigned long long pack64(float v, int k) {
  unsigned int b = __float_as_uint(v);
  b = (b & 0x80000000u) ? ~b : (b | 0x80000000u);   // order-preserving map
  return ((unsigned long long)b << 32) | (unsigned int)k;
}

__device__ __forceinline__ float unpack32(unsigned int p) {
  p = (p & 0x80000000u) ? (p ^ 0x80000000u) : ~p;
  return __uint_as_float(p);
}

__device__ __forceinline__ float blockReduceSum(float v, volatile float* sred) {
  #pragma unroll
  for (int off = 32; off > 0; off >>= 1) v += __shfl_down(v, off, 64);
  __syncthreads();
  if ((threadIdx.x & 63) == 0) sred[threadIdx.x >> 6] = v;
  __syncthreads();
  float r = 0.0f;
  if (threadIdx.x == 0) {
    const int nw = blockDim.x >> 6;
    for (int i = 0; i < nw; ++i) r += sred[i];
  }
  return r;  // valid on thread 0 only
}

// ---------------------------------------------------------------------------
// prep (unchanged from R11/R12): blocks 0..255 stream z, LDS-transpose, emit
// Z2 (bf16, exact Zs fragment order) + zn2p + z stats.  Blocks 256..319: E.
// ---------------------------------------------------------------------------
__global__ __launch_bounds__(512)
void vq_prep(const float* __restrict__ z, const float* __restrict__ e,
             unsigned short* __restrict__ E2, unsigned short* __restrict__ Z2,
             float* __restrict__ enorm, float* __restrict__ sum_e_d,
             float* __restrict__ sum_z_d, float* __restrict__ zn2p,
             double* __restrict__ scald) {
  __shared__ float tile[32][129];     // 16.5 KB transpose tile (+1 pad: 2-way free)
  __shared__ float ered[16][33];
  __shared__ float sumed[256];
  __shared__ float sred[8];
  const int t   = threadIdx.x;
  const int blk = blockIdx.x;

  if (blk < 256) {
    // ---- z block: b = blk>>3, ds = blk&7 (32-d slice x 1024 hw) ----
    const int b = blk >> 3, ds = blk & 7;
    const int r = t >> 4, c = t & 15;          // load identity (rows of z)
    const int l = t & 63;
    const int hwblk_l = t >> 8;                 // transpose identity: 0/1
    const int slot = t & 255;
    const int squad = (l >> 4) & 3;             // = (slot>>4)&3
    const int ni = slot >> 6;                   // const per wave
    const int n15 = l & 15;
    const int hw_loc = hwblk_l * 64 + ni * 16 + n15;
    const float* zr = z + ((size_t)(b * D_ + ds * 32 + r)) * HW_;

    float srow = 0.0f, s2 = 0.0f;
    float4 f0 = *(const float4*)(zr + c * 4);
    float4 f1 = *(const float4*)(zr + c * 4 + 64);
    #pragma unroll 1
    for (int iter = 0; iter < 8; ++iter) {
      // accumulate row stats + stage tile
      srow += (f0.x + f0.y) + (f0.z + f0.w) + (f1.x + f1.y) + (f1.z + f1.w);
      s2 += f0.x*f0.x + f0.y*f0.y + f0.z*f0.z + f0.w*f0.w
          + f1.x*f1.x + f1.y*f1.y + f1.z*f1.z + f1.w*f1.w;
      float* td = &tile[r][c * 4];
      td[0]=f0.x; td[1]=f0.y; td[2]=f0.z; td[3]=f0.w;
      td[64]=f1.x; td[65]=f1.y; td[66]=f1.z; td[67]=f1.w;
      __syncthreads();
      // prefetch next tile (latency hides under transpose phase)
      if (iter < 7) {
        f0 = *(const float4*)(zr + (iter+1) * 128 + c * 4);
        f1 = *(const float4*)(zr + (iter+1) * 128 + c * 4 + 64);
      }
      // transpose out: 8 d-consecutive values for (hw_loc) -> one bf16x8
      float v[8]; float zsq = 0.0f;
      #pragma unroll
      for (int j = 0; j < 8; ++j) {
        v[j] = tile[squad * 8 + j][hw_loc];     // banks 2-way (129%32==1)
        zsq = fmaf(v[j], v[j], zsq);
      }
      unsigned int wd[4];
      #pragma unroll
      for (int j2 = 0; j2 < 4; ++j2)
        wd[j2] = (unsigned int)f2bf(v[2*j2]) | ((unsigned int)f2bf(v[2*j2+1]) << 16);
      const size_t zi = (((size_t)(b * 16 + iter * 2 + hwblk_l)) * 8 + ds) * 256 + slot;
      *(u32x4*)(Z2 + zi * 8) = *(u32x4*)wd;     // 16B coalesced store
      // per-n ||z||^2 partial over this block's 32 d: reduce across squads
      zsq += __shfl_xor(zsq, 16, 64);
      zsq += __shfl_xor(zsq, 32, 64);
      if (squad == 0)
        zn2p[ds * N_ + b * HW_ + iter * 128 + hw_loc] = zsq;  // unique writer
      __syncthreads();
    }
    float ssum = srow;
    #pragma unroll
    for (int off = 1; off < 16; off <<= 1) ssum += __shfl_xor(ssum, off, 16);
    if (c == 0) atomicAdd(&sum_z_d[ds * 32 + r], ssum);
    const float rs2 = blockReduceSum(s2, sred);
    if (t == 0) atomicAdd(&scald[1], (double)rs2);
  } else {
    // ---- E block (kt = blk-256): R0 E-part verbatim ----
    const int kt = blk - 256;
    const int ds = t >> 6, l = t & 63;
    const int q  = l >> 4, m = l & 15;
    const int k  = kt * 16 + m;
    const int d0 = ds * 32 + q * 8;
    if (t < 256) sumed[t] = 0.0f;
    __syncthreads();

    const float* ep = e + (size_t)k * D_ + d0;
    const float4 v0 = *(const float4*)ep;
    const float4 v1 = *(const float4*)(ep + 4);
    const float vv[8] = {v0.x, v0.y, v0.z, v0.w, v1.x, v1.y, v1.z, v1.w};
    short hv[8];
    float p = 0.0f;
    #pragma unroll
    for (int j = 0; j < 8; ++j) {
      const float f = vv[j];
      p += f * f;
      hv[j] = (short)f2bf(f);
      float s = f;
      #pragma unroll
      for (int off = 1; off < 16; off <<= 1) s += __shfl_xor(s, off, 16);
      if ((l & 15) == 0) atomicAdd(&sumed[d0 + j], s);
    }
    const size_t fi = ((size_t)(kt * 8 + ds)) * 64 + l;
    *(bf16x8*)(E2 + fi * 8) = *(bf16x8*)hv;

    ered[m][ds * 4 + q] = p;
    __syncthreads();
    if (t < 16) {
      float s = 0.0f;
      #pragma unroll
      for (int i = 0; i < 32; ++i) s += ered[t][i];
      enorm[kt * 16 + t] = s;
    }
    if (t < 256) atomicAdd(&sum_e_d[t], sumed[t]);
  }
}

// ---------------------------------------------------------------------------
// R13 argmin: R12 + B-fragment LDS reads via inline-asm ds_read2_b32.
// R12 post-mortem: B/C LDS pillar = 4096 frag-reads/CU x 4 ds_read_b32 x
// 5.8cyc = 9.9us (R11->R12 delta matched the scalar-b32 model).  ds_read2_b32
// moves 2 dwords/instr at the same per-instr cost and keeps the stride-5
// bank pattern (2-way, free) -- unlike b128, which R7 measured 8-way aliased.
// Compiler can't merge odd-aligned stride-5 dwords itself -> inline asm with
// "=&v" early-clobber, s_waitcnt lgkmcnt(0) + sched_barrier(0) before the
// MFMA cluster (guide rule #18: compiler hoists reg-only MFMA past asm waits).
// Everything else byte-identical to R12.
// ---------------------------------------------------------------------------
__global__ __launch_bounds__(512, 4)
void vq_argmin8(const float* __restrict__ e,
                const unsigned short* __restrict__ E2,
                const unsigned short* __restrict__ Z2,
                const float* __restrict__ enorm_g,
                const float* __restrict__ zn2p,
                float* __restrict__ out, unsigned int* __restrict__ counts,
                float* __restrict__ sum_e_d, float* __restrict__ sum_z_d,
                double* __restrict__ scald, unsigned int* __restrict__ done) {
  union SM {
    unsigned int Zs[8][1280];       // 40960 B: [ds][slot*5 + dword]
    float erow[32 * 257];           // 32896 B (epilogue staging, 32 n / pass)
  };
  __shared__ SM sm;
  __shared__ float en[1024];
  __shared__ unsigned long long red[8][64];
  __shared__ unsigned int kbuf[64];
  __shared__ float rs[8];
  __shared__ int sflag;

  const int t  = threadIdx.x;
  const int nt = blockIdx.x;
  const int b   = nt >> 4;
  const int hw0 = (nt & 15) << 6;
  const int w = t >> 6, l = t & 63;
  const int quad = l >> 4;
  const int slot = t & 255;
  const int jh   = t >> 8;

  en[t] = enorm_g[t];
  en[t + 512] = enorm_g[t + 512];

  // ---- Phase A: 4 x bf16x8 coalesced loads of pre-packed Z2 -> Zs ----
  {
    const bf16x8* __restrict__ Z8 = (const bf16x8*)Z2;
    const size_t z2b = (((size_t)(b * 16 + (nt & 15))) * 8) * 256;
    #pragma unroll
    for (int i = 0; i < 4; ++i) {
      const int ds = i * 2 + jh;
      const u32x4 wv = __builtin_bit_cast(u32x4, Z8[z2b + (size_t)ds * 256 + slot]);
      unsigned int* zp = &sm.Zs[ds][slot * 5];
      zp[0] = wv.x; zp[1] = wv.y; zp[2] = wv.z; zp[3] = wv.w;  // banks 2-way, free
    }
  }
  __syncthreads();

  // ---- Phase B/C: 2 passes of 128k x 64n (kti=4), fold between passes ----
  const bf16x8* __restrict__ E8 = (const bf16x8*)E2;

  // per-ni LDS byte addresses of this lane's B fragments (stride-5 layout)
  unsigned zsb_ni[4];
  {
    const unsigned zbase = (unsigned)(size_t)(&sm.Zs[0][0]);
    #pragma unroll
    for (int ni = 0; ni < 4; ++ni)
      zsb_ni[ni] = zbase + (unsigned)(((ni * 64 + l) * 5) * 4);
  }

  float bestv[4];
  int   bestk[4];
  #pragma unroll
  for (int ni = 0; ni < 4; ++ni) { bestv[ni] = 3.0e38f; bestk[ni] = 0; }

  #pragma unroll 1
  for (int p = 0; p < 2; ++p) {
    // ktg strictly ascending per thread across p and kti => tiebreak holds
    const int ktg0 = p * 32 + w * 4;

    f32x4 acc[4][4];
    #pragma unroll
    for (int kti = 0; kti < 4; ++kti)
      #pragma unroll
      for (int ni = 0; ni < 4; ++ni) acc[kti][ni] = (f32x4)0.0f;

    #pragma unroll 2
    for (int ds = 0; ds < 8; ++ds) {
      bf16x8 Av[4];
      #pragma unroll
      for (int kti = 0; kti < 4; ++kti)
        Av[kti] = E8[(size_t)((ktg0 + kti) * 8 + ds) * 64 + l];
      // issue all 8 ds_read2_b32 (2 per ni), then one wait, then MFMA cluster
      u32x2 pa[4], pb[4];
      #pragma unroll
      for (int ni = 0; ni < 4; ++ni) {
        const unsigned va = zsb_ni[ni] + (unsigned)(ds * 5120);
        asm volatile("ds_read2_b32 %0, %2 offset0:0 offset1:1\n\t"
                     "ds_read2_b32 %1, %2 offset0:2 offset1:3"
                     : "=&v"(pa[ni]), "=&v"(pb[ni]) : "v"(va));
      }
      asm volatile("s_waitcnt lgkmcnt(0)" ::: "memory");
      __builtin_amdgcn_sched_barrier(0);
      #pragma unroll
      for (int ni = 0; ni < 4; ++ni) {
        u32x4 bw;
        bw.x = pa[ni].x; bw.y = pa[ni].y; bw.z = pb[ni].x; bw.w = pb[ni].y;
        const bf16x8 Bv = __builtin_bit_cast(bf16x8, bw);
        #pragma unroll
        for (int kti = 0; kti < 4; ++kti)
          acc[kti][ni] = __builtin_amdgcn_mfma_f32_16x16x32_bf16(Av[kti], Bv,
                                                                acc[kti][ni], 0, 0, 0);
      }
    }
    // fold this pass (k ascending within pass as well)
    #pragma unroll
    for (int kti = 0; kti < 4; ++kti) {
      const int kb = (ktg0 + kti) * 16 + quad * 4;
      const f32x4 en4 = *(const f32x4*)&en[kb];
      #pragma unroll
      for (int ni = 0; ni < 4; ++ni) {
        const f32x4 a = acc[kti][ni];
        #pragma unroll
        for (int r = 0; r < 4; ++r) {
          const float v = fmaf(-2.0f, a[r], en4[r]);
          if (v < bestv[ni]) { bestv[ni] = v; bestk[ni] = kb + r; }
        }
      }
    }
  }

  #pragma unroll
  for (int ni = 0; ni < 4; ++ni) {
    unsigned long long p = pack64(bestv[ni], bestk[ni]);
    unsigned long long p2 = __shfl_down(p, 32, 64); if (p2 < p) p = p2;
    p2 = __shfl_down(p, 16, 64);                    if (p2 < p) p = p2;
    if (quad == 0) red[w][ni * 16 + (l & 15)] = p;
  }
  __syncthreads();   // red ready; all Zs reads done

  if (t < 64) {
    unsigned long long m = red[0][t];
    #pragma unroll
    for (int i = 1; i < 8; ++i) { const unsigned long long c = red[i][t]; if (c < m) m = c; }
    const unsigned int k = (unsigned int)(m & 0xFFFFFFFFull);
    kbuf[t] = k;
    atomicAdd(&counts[k], 1u);
    const float dminv = unpack32((unsigned int)(m >> 32));
    float zn2v = 0.0f;
    #pragma unroll
    for (int ds = 0; ds < 8; ++ds) zn2v += zn2p[ds * N_ + b * HW_ + hw0 + t];
    float dsum = zn2v + dminv;       // ||z_n - e_k||^2 (analytic)
    #pragma unroll
    for (int off = 32; off > 0; off >>= 1) dsum += __shfl_down(dsum, off, 64);
    if (t == 0) atomicAdd(&scald[2], (double)dsum);
  }
  __syncthreads();   // kbuf ready; Zs dead -> erow may overwrite

  // ---- Phase D: two 32-n passes: stage chosen e-rows, write coalesced ----
  #pragma unroll 1
  for (int p = 0; p < 2; ++p) {
    {
      const int r = t >> 4;             // 0..31 (n within pass)
      const int c = t & 15;
      const unsigned int k = kbuf[p * 32 + r];
      const float* er = e + (size_t)k * D_ + c * 4;
      #pragma unroll
      for (int i = 0; i < 4; ++i) {
        const float4 f = *(const float4*)(er + i * 64);
        float* dst = &sm.erow[r * 257 + c * 4 + i * 64];
        dst[0] = f.x; dst[1] = f.y; dst[2] = f.z; dst[3] = f.w;  // banks r+4c+j: 2-way
      }
    }
    __syncthreads();
    {
      const int s  = t >> 5;            // 0..15 -> d-slice of 16
      const int cc = t & 31;            // hw within pass
      float* ob = out + ((size_t)b * D_ + s * 16) * HW_ + hw0 + p * 32 + cc;
      #pragma unroll
      for (int i = 0; i < 16; ++i)
        ob[(size_t)i * HW_] = sm.erow[cc * 257 + s * 16 + i];
    }
    __syncthreads();
  }

  // ---- last-of-512 ticket -> finalize (NO threadfence: atomics only) ----
  if (t == 0) {
    asm volatile("s_waitcnt vmcnt(0)" ::: "memory");
    const unsigned int r = atomicAdd(done, 1u);
    sflag = (r == (GRID_MAIN - 1)) ? 1 : 0;
  }
  __syncthreads();
  if (sflag) {
    // entropy of e_mean (atomic RMW reads: coherent-point, no stale L2)
    float h = 0.0f;
    for (int i = t; i < K_; i += 512) {
      const float em = (float)atomicAdd(&counts[i], 0u) * (1.0f / (float)N_);
      h += em * logf(em + 1e-10f);
    }
    const float hs = blockReduceSum(h, rs);
    __syncthreads();
    float dv = 0.0f;
    if (t < 256) dv = atomicAdd(&sum_z_d[t], 0.0f) * sum_e_d[t];
    const float dot = blockReduceSum(dv, rs);
    __syncthreads();
    const float e2 = enorm_g[t] + enorm_g[t + 512];
    const float sume2 = blockReduceSum(e2, rs);
    if (t == 0) {
      const double sz2 = atomicAdd(&scald[1], 0.0);
      const double sd2 = atomicAdd(&scald[2], 0.0);
      const double loss = (double)(1.0f + BETA_) * sd2 / (double)((size_t)N_ * D_);
      const double md = sz2 / (double)N_ + (double)sume2 / (double)K_
                      - 2.0 * (double)dot / ((double)N_ * (double)K_);
      out[OUT0 + 0] = (float)loss;
      out[OUT0 + 1] = expf(-hs);
      out[OUT0 + 2] = (float)md;
    }
  }
}

extern "C" void kernel_launch(void* const* d_in, const int* in_sizes, int n_in,
                              void* d_out, int out_size, void* d_ws, size_t ws_size,
                              hipStream_t stream) {
  const float* z = (const float*)d_in[0];        // [32,256,32,32]
  const float* e = (const float*)d_in[1];        // [1024,256]
  float* out = (float*)d_out;

  char* ws = (char*)d_ws;
  unsigned short* E2 = (unsigned short*)(ws + E2_OFF);
  unsigned short* Z2 = (unsigned short*)(ws + Z2_OFF);
  float* enorm   = (float*)(ws + ENORM_OFF);
  float* sum_e_d = (float*)(ws + SUMED_OFF);
  float* sum_z_d = (float*)(ws + SUMZD_OFF);
  float* zn2p    = (float*)(ws + ZN2P_OFF);
  unsigned int* counts = (unsigned int*)(ws + CNT_OFF);
  double* scald  = (double*)(ws + SCAL_OFF);
  unsigned int* done = (unsigned int*)(ws + DONE_OFF);

  hipMemsetAsync(ws + ZERO_OFF, 0x00, (size_t)ZERO_BYTES, stream);

  vq_prep    <<<dim3(GRID_PREP), dim3(512), 0, stream>>>(z, e, E2, Z2, enorm,
                                                         sum_e_d, sum_z_d, zn2p, scald);
  vq_argmin8 <<<dim3(GRID_MAIN), dim3(512), 0, stream>>>(e, E2, Z2, enorm, zn2p,
                                                         out, counts, sum_e_d,
                                                         sum_z_d, scald, done);
}

// Round 24
// 120.388 us; speedup vs baseline: 1.0796x; 1.0662x over previous
//
#include <hip/hip_runtime.h>
#include <stdint.h>

#define B_    32
#define D_    256
#define HW_   1024
#define N_    32768      // B_*HW_
#define K_    1024
#define BETA_ 0.25f
#define OUT0  8388608    // N_*D_

typedef short bf16x8 __attribute__((ext_vector_type(8)));
typedef unsigned int u32x4 __attribute__((ext_vector_type(4)));
typedef unsigned int u32x2 __attribute__((ext_vector_type(2)));
typedef float f32x4  __attribute__((ext_vector_type(4)));

// ---- workspace layout (bytes) ----
#define E2_OFF    0          // 512 KB  bf16 of E, A-fragment order (k-major)
#define ENORM_OFF 524288     // 4 KB    ||e_k||^2 fp32 (exact, from fp32 e)
#define SUMED_OFF 528384     // 1 KB    col sums of E
#define SUMZD_OFF 529408     // 1 KB    per-d sums of Z
#define CNT_OFF   530432     // 4 KB    histogram
#define SCAL_OFF  534528     // 32 B    doubles: [1]=sum z^2, [2]=sum diff^2
#define ZERO_OFF  SUMED_OFF
#define ZERO_BYTES (534560 - SUMED_OFF)

__device__ __forceinline__ unsigned short f2bf(float f) {
  unsigned int u = __float_as_uint(f);
  u += 0x7FFFu + ((u >> 16) & 1u);          // round-to-nearest-even
  return (unsigned short)(u >> 16);
}

__device__ __forceinline__ unsigned long long pack64(float v, int k) {
  unsigned int b = __float_as_uint(v);
  b = (b & 0x80000000u) ? ~b : (b | 0x80000000u);   // order-preserving map
  return ((unsigned long long)b << 32) | (unsigned int)k;
}

__device__ __forceinline__ float unpack32(unsigned int p) {
  p = (p & 0x80000000u) ? (p ^ 0x80000000u) : ~p;
  return __uint_as_float(p);
}

__device__ __forceinline__ float blockReduceSum(float v, volatile float* sred) {
  #pragma unroll
  for (int off = 32; off > 0; off >>= 1) v += __shfl_down(v, off, 64);
  __syncthreads();
  if ((threadIdx.x & 63) == 0) sred[threadIdx.x >> 6] = v;
  __syncthreads();
  float r = 0.0f;
  if (threadIdx.x == 0) {
    const int nw = blockDim.x >> 6;
    for (int i = 0; i < nw; ++i) r += sred[i];
  }
  return r;  // valid on thread 0 only
}

// ---------------------------------------------------------------------------
// R14: REVERT to the R0 pipeline shape (best measured total: 121.8us).
// Post-mortem R10-R13: argmin8 went 52.4 -> <42.2 but dur_us stayed ~128;
// argmin8's duration is not 1:1 on the harness critical path, and R0's
// 3-kernel shape (eprep streams z -> argmin8 reads warm z in-kernel ->
// tiny final) times best.  Keep R0 verbatim EXCEPT graft the two changes
// proven to cut argmin8's own time: kti=4 2-pass B/C (R12: -7.4us) and
// inline-asm ds_read2_b32 B-fragment reads (R13).
// ---------------------------------------------------------------------------
// E prep + Z stats.  grid 256 x 512.  (R0 verbatim)
// ---------------------------------------------------------------------------
__global__ __launch_bounds__(512)
void vq_eprep(const float* __restrict__ e, const float* __restrict__ z,
              unsigned short* __restrict__ E2, float* __restrict__ enorm,
              float* __restrict__ sum_e_d, float* __restrict__ sum_z_d,
              double* __restrict__ scald) {
  __shared__ float ered[16][33];
  __shared__ float sumed[256];
  __shared__ float sred[8];
  const int t   = threadIdx.x;
  const int blk = blockIdx.x;

  if (blk < 64) {                      // ---- E-part (block-uniform branch) ----
    const int kt = blk;
    const int ds = t >> 6, l = t & 63;
    const int q  = l >> 4, m = l & 15;
    const int k  = kt * 16 + m;
    const int d0 = ds * 32 + q * 8;
    if (t < 256) sumed[t] = 0.0f;
    __syncthreads();

    const float* ep = e + (size_t)k * D_ + d0;
    const float4 v0 = *(const float4*)ep;
    const float4 v1 = *(const float4*)(ep + 4);
    const float vv[8] = {v0.x, v0.y, v0.z, v0.w, v1.x, v1.y, v1.z, v1.w};
    short hv[8];
    float p = 0.0f;
    #pragma unroll
    for (int j = 0; j < 8; ++j) {
      const float f = vv[j];
      p += f * f;
      hv[j] = (short)f2bf(f);
      float s = f;
      #pragma unroll
      for (int off = 1; off < 16; off <<= 1) s += __shfl_xor(s, off, 16);
      if ((l & 15) == 0) atomicAdd(&sumed[d0 + j], s);
    }
    const size_t fi = ((size_t)(kt * 8 + ds)) * 64 + l;
    *(bf16x8*)(E2 + fi * 8) = *(bf16x8*)hv;

    ered[m][ds * 4 + q] = p;
    __syncthreads();
    if (t < 16) {
      float s = 0.0f;
      #pragma unroll
      for (int i = 0; i < 32; ++i) s += ered[t][i];
      enorm[kt * 16 + t] = s;
    }
    if (t < 256) atomicAdd(&sum_e_d[t], sumed[t]);
  }

  // ---- Z-stats part (all blocks): 32 (b,d)-rows of 1024 floats ----
  {
    const int b  = blk >> 3;
    const int dg = (blk & 7) << 5;
    const int r  = t >> 4;             // 0..31 row within slice
    const int c  = t & 15;             // 16 lanes share a row (one quad)
    const float* zr = z + ((size_t)(b * D_ + dg + r)) * HW_;
    float s = 0.0f, s2 = 0.0f;
    #pragma unroll 4
    for (int i = 0; i < 16; ++i) {
      const float4 f = *(const float4*)(zr + i * 64 + c * 4);
      s  += (f.x + f.y) + (f.z + f.w);
      s2 += f.x * f.x + f.y * f.y + f.z * f.z + f.w * f.w;
    }
    float ssum = s;
    #pragma unroll
    for (int off = 1; off < 16; off <<= 1) ssum += __shfl_xor(ssum, off, 16);
    if (c == 0) atomicAdd(&sum_z_d[dg + r], ssum);
    const float rs2 = blockReduceSum(s2, sred);
    if (t == 0) atomicAdd(&scald[1], (double)rs2);
  }
}

// ---------------------------------------------------------------------------
// Fused argmin + gather.  R0 body with B/C upgraded to kti=4 + ds_read2_b32.
// ---------------------------------------------------------------------------
__global__ __launch_bounds__(512, 4)
void vq_argmin8(const float* __restrict__ z, const float* __restrict__ e,
                const unsigned short* __restrict__ E2,
                const float* __restrict__ enorm_g,
                float* __restrict__ out, unsigned int* __restrict__ counts,
                double* __restrict__ scald) {
  union SM {
    unsigned int Zs[8][1280];       // 40960 B: [ds][slot*5 + dword]
    float erow[32 * 257];           // 32896 B (epilogue staging, 32 n / pass)
  };
  __shared__ SM sm;
  __shared__ float en[1024];
  __shared__ unsigned long long red[8][64];
  __shared__ float zn2[64];
  __shared__ unsigned int kbuf[64];

  const int t  = threadIdx.x;
  const int nt = blockIdx.x;
  const int b   = nt >> 4;
  const int hw0 = (nt & 15) << 6;
  const int w = t >> 6, l = t & 63;
  const int quad = l >> 4;

  // staging identity
  const int slot  = t & 255;
  const int jh    = t >> 8;                            // 0/1 -> j = jh*4 + c
  const int squad = (slot >> 4) & 3;
  const int nloc  = ((slot >> 6) << 4) + (slot & 15);  // ni*16 + n15
  const float* zb = z + (size_t)b * D_ * HW_ + hw0 + nloc;

  if (t < 64)  zn2[t] = 0.0f;
  en[t] = enorm_g[t];
  en[t + 512] = enorm_g[t + 512];
  __syncthreads();

  // ---- Phase A: stage all of Z (single bf16, stride-5 dword layout) ----
  float zn2acc = 0.0f;
  #pragma unroll 1
  for (int ds = 0; ds < 8; ++ds) {
    const int dbase = ds * 32 + squad * 8 + jh * 4;
    float f[4];
    #pragma unroll
    for (int c = 0; c < 4; ++c) f[c] = zb[(size_t)(dbase + c) * HW_];
    #pragma unroll
    for (int c = 0; c < 4; ++c) zn2acc = fmaf(f[c], f[c], zn2acc);
    const unsigned int w0 = (unsigned int)f2bf(f[0]) | ((unsigned int)f2bf(f[1]) << 16);
    const unsigned int w1 = (unsigned int)f2bf(f[2]) | ((unsigned int)f2bf(f[3]) << 16);
    unsigned int* zp = &sm.Zs[ds][slot * 5 + jh * 2];
    zp[0] = w0;                       // banks (5*slot + 2jh + j) % 32: 2-way, free
    zp[1] = w1;
  }
  atomicAdd(&zn2[nloc], zn2acc);     // 4-way same-address only
  __syncthreads();

  // ---- Phase B/C: 2 passes of 128k x 64n (kti=4), fold between passes ----
  const bf16x8* __restrict__ E8 = (const bf16x8*)E2;

  // per-ni LDS byte addresses of this lane's B fragments (stride-5 layout)
  unsigned zsb_ni[4];
  {
    const unsigned zbase = (unsigned)(size_t)(&sm.Zs[0][0]);
    #pragma unroll
    for (int ni = 0; ni < 4; ++ni)
      zsb_ni[ni] = zbase + (unsigned)(((ni * 64 + l) * 5) * 4);
  }

  float bestv[4];
  int   bestk[4];
  #pragma unroll
  for (int ni = 0; ni < 4; ++ni) { bestv[ni] = 3.0e38f; bestk[ni] = 0; }

  #pragma unroll 1
  for (int p = 0; p < 2; ++p) {
    // ktg strictly ascending per thread across p and kti => tiebreak holds
    const int ktg0 = p * 32 + w * 4;

    f32x4 acc[4][4];
    #pragma unroll
    for (int kti = 0; kti < 4; ++kti)
      #pragma unroll
      for (int ni = 0; ni < 4; ++ni) acc[kti][ni] = (f32x4)0.0f;

    #pragma unroll 2
    for (int ds = 0; ds < 8; ++ds) {
      bf16x8 Av[4];
      #pragma unroll
      for (int kti = 0; kti < 4; ++kti)
        Av[kti] = E8[(size_t)((ktg0 + kti) * 8 + ds) * 64 + l];
      // issue all 8 ds_read2_b32 (2 per ni), then one wait, then MFMA cluster
      u32x2 pa[4], pb[4];
      #pragma unroll
      for (int ni = 0; ni < 4; ++ni) {
        const unsigned va = zsb_ni[ni] + (unsigned)(ds * 5120);
        asm volatile("ds_read2_b32 %0, %2 offset0:0 offset1:1\n\t"
                     "ds_read2_b32 %1, %2 offset0:2 offset1:3"
                     : "=&v"(pa[ni]), "=&v"(pb[ni]) : "v"(va));
      }
      asm volatile("s_waitcnt lgkmcnt(0)" ::: "memory");
      __builtin_amdgcn_sched_barrier(0);
      #pragma unroll
      for (int ni = 0; ni < 4; ++ni) {
        u32x4 bw;
        bw.x = pa[ni].x; bw.y = pa[ni].y; bw.z = pb[ni].x; bw.w = pb[ni].y;
        const bf16x8 Bv = __builtin_bit_cast(bf16x8, bw);
        #pragma unroll
        for (int kti = 0; kti < 4; ++kti)
          acc[kti][ni] = __builtin_amdgcn_mfma_f32_16x16x32_bf16(Av[kti], Bv,
                                                                acc[kti][ni], 0, 0, 0);
      }
    }
    // fold this pass (k ascending within pass as well)
    #pragma unroll
    for (int kti = 0; kti < 4; ++kti) {
      const int kb = (ktg0 + kti) * 16 + quad * 4;
      const f32x4 en4 = *(const f32x4*)&en[kb];
      #pragma unroll
      for (int ni = 0; ni < 4; ++ni) {
        const f32x4 a = acc[kti][ni];
        #pragma unroll
        for (int r = 0; r < 4; ++r) {
          const float v = fmaf(-2.0f, a[r], en4[r]);
          if (v < bestv[ni]) { bestv[ni] = v; bestk[ni] = kb + r; }
        }
      }
    }
  }

  #pragma unroll
  for (int ni = 0; ni < 4; ++ni) {
    unsigned long long p = pack64(bestv[ni], bestk[ni]);
    unsigned long long p2 = __shfl_down(p, 32, 64); if (p2 < p) p = p2;
    p2 = __shfl_down(p, 16, 64);                    if (p2 < p) p = p2;
    if (quad == 0) red[w][ni * 16 + (l & 15)] = p;
  }
  __syncthreads();   // red + zn2 ready; all Zs reads done

  if (t < 64) {
    unsigned long long m = red[0][t];
    #pragma unroll
    for (int i = 1; i < 8; ++i) { const unsigned long long c = red[i][t]; if (c < m) m = c; }
    const unsigned int k = (unsigned int)(m & 0xFFFFFFFFull);
    kbuf[t] = k;
    atomicAdd(&counts[k], 1u);
    const float dminv = unpack32((unsigned int)(m >> 32));
    float dsum = zn2[t] + dminv;     // ||z_n - e_k||^2 (analytic)
    #pragma unroll
    for (int off = 32; off > 0; off >>= 1) dsum += __shfl_down(dsum, off, 64);
    if (t == 0) atomicAdd(&scald[2], (double)dsum);
  }
  __syncthreads();   // kbuf ready; Zs dead -> erow may overwrite

  // ---- Phase D: two 32-n passes: stage chosen e-rows, write out coalesced ----
  #pragma unroll 1
  for (int p = 0; p < 2; ++p) {
    {
      const int r = t >> 4;             // 0..31 (n within pass)
      const int c = t & 15;
      const unsigned int k = kbuf[p * 32 + r];
      const float* er = e + (size_t)k * D_ + c * 4;
      #pragma unroll
      for (int i = 0; i < 4; ++i) {
        const float4 f = *(const float4*)(er + i * 64);
        float* dst = &sm.erow[r * 257 + c * 4 + i * 64];
        dst[0] = f.x; dst[1] = f.y; dst[2] = f.z; dst[3] = f.w;  // banks r+4c+j: 2-way
      }
    }
    __syncthreads();
    {
      const int s  = t >> 5;            // 0..15 -> d-slice of 16
      const int cc = t & 31;            // hw within pass
      float* ob = out + ((size_t)b * D_ + s * 16) * HW_ + hw0 + p * 32 + cc;
      #pragma unroll
      for (int i = 0; i < 16; ++i)
        ob[(size_t)i * HW_] = sm.erow[cc * 257 + s * 16 + i];
    }
    if (p == 0) __syncthreads();
  }
}

// ---------------------------------------------------------------------------
// finalize: loss, perplexity, mean_distance  (R0 verbatim)
// ---------------------------------------------------------------------------
__global__ void vq_final(const unsigned int* __restrict__ counts,
                         const float* __restrict__ enorm,
                         const float* __restrict__ sum_e_d, const float* __restrict__ sum_z_d,
                         const double* __restrict__ scald, float* __restrict__ out) {
  __shared__ float sred[4];
  const int t = threadIdx.x;
  float h = 0.0f;
  for (int i = t; i < K_; i += 256) {
    const float em = (float)counts[i] * (1.0f / (float)N_);
    h += em * logf(em + 1e-10f);
  }
  const float hs = blockReduceSum(h, sred);
  __syncthreads();
  const float dv = sum_z_d[t] * sum_e_d[t];
  const float dot = blockReduceSum(dv, sred);
  __syncthreads();
  float e2 = 0.0f;
  #pragma unroll
  for (int i = 0; i < 4; ++i) e2 += enorm[t + 256 * i];
  const float sume2 = blockReduceSum(e2, sred);
  if (t == 0) {
    const double loss = (double)(1.0f + BETA_) * scald[2] / (double)((size_t)N_ * D_);
    const float perp = expf(-hs);
    const double md = scald[1] / (double)N_ + (double)sume2 / (double)K_
                    - 2.0 * (double)dot / ((double)N_ * (double)K_);
    out[OUT0 + 0] = (float)loss;
    out[OUT0 + 1] = perp;
    out[OUT0 + 2] = (float)md;
  }
}

extern "C" void kernel_launch(void* const* d_in, const int* in_sizes, int n_in,
                              void* d_out, int out_size, void* d_ws, size_t ws_size,
                              hipStream_t stream) {
  const float* z = (const float*)d_in[0];        // [32,256,32,32]
  const float* e = (const float*)d_in[1];        // [1024,256]
  float* out = (float*)d_out;

  char* ws = (char*)d_ws;
  unsigned short* E2 = (unsigned short*)(ws + E2_OFF);
  float* enorm   = (float*)(ws + ENORM_OFF);
  float* sum_e_d = (float*)(ws + SUMED_OFF);
  float* sum_z_d = (float*)(ws + SUMZD_OFF);
  unsigned int* counts = (unsigned int*)(ws + CNT_OFF);
  double* scald  = (double*)(ws + SCAL_OFF);

  hipMemsetAsync(ws + ZERO_OFF, 0x00, (size_t)ZERO_BYTES, stream);

  vq_eprep   <<<dim3(256), dim3(512), 0, stream>>>(e, z, E2, enorm, sum_e_d,
                                                   sum_z_d, scald);
  vq_argmin8 <<<dim3(512), dim3(512), 0, stream>>>(z, e, E2, enorm, out, counts,
                                                   scald);
  vq_final   <<<dim3(1),   dim3(256), 0, stream>>>(counts, enorm, sum_e_d, sum_z_d,
                                                   scald, out);
}